// Round 6
// baseline (232.848 us; speedup 1.0000x reference)
//
#include <hip/hip_runtime.h>

#define HEADS 4

// ---------- helpers ----------
__device__ __forceinline__ unsigned short f2bf(float f) {   // fp32 -> bf16 RNE
    unsigned u = __float_as_uint(f);
    return (unsigned short)((u + 0x7FFFu + ((u >> 16) & 1u)) >> 16);
}
// per-wave int64-layout detection: odd 32-bit words of first 64 entries all zero
__device__ __forceinline__ int detect64(const int* __restrict__ ei32) {
    unsigned long long b = __ballot(ei32[2 * (threadIdx.x & 63) + 1] != 0);
    return (b == 0ULL) ? 1 : 0;     // wave-uniform
}
__device__ __forceinline__ void load_edge(const void* ei, int is64, long E, long e,
                                          long* s, long* d) {
    if (is64) {
        *s = (long)((const long long*)ei)[e];
        *d = (long)((const long long*)ei)[E + e];
    } else {
        *s = (long)((const int*)ei)[e];
        *d = (long)((const int*)ei)[E + e];
    }
}

// ---------- fused x@W.T + node scores (blocks [0,NG)) + dst histogram (rest) ----------
// gemm: lane = node (64/block); wave wid = head, owns features [wid*32, wid*32+32).
// x direct from global (L1-shared across the 4 waves); W via wave-uniform s_load.
// xt stored as packed bf16x2 (row = 256B) — only consumer is k_gather.
__launch_bounds__(256)
__global__ void k_gemm_hist(const float* __restrict__ x, const float* __restrict__ W,
                            const float* __restrict__ avs, const float* __restrict__ avd,
                            const void* __restrict__ ei, unsigned* __restrict__ xt16,
                            float* __restrict__ ss, float* __restrict__ sd,
                            int* __restrict__ deg, int N, int NG, long E) {
    if ((int)blockIdx.x >= NG) {            // ---- histogram blocks ----
        const int is64 = detect64((const int*)ei);
        const long e = (long)((int)blockIdx.x - NG) * 256 + threadIdx.x;
        if (e < E) {
            long d;
            if (is64) d = (long)((const long long*)ei)[E + e];
            else      d = (long)((const int*)ei)[E + e];
            atomicAdd(&deg[(int)d], 1);
        }
        return;
    }
    // ---- gemm blocks ----
    const int tid = threadIdx.x;
    const int lane = tid & 63;
    const int wid = __builtin_amdgcn_readfirstlane(tid >> 6);  // 0..3 = head
    const int n = blockIdx.x * 64 + lane;
    const bool act = (n < N);
    const float4* __restrict__ xg = (const float4*)(x + (long)n * 128);
    const float* __restrict__ Wb = W + wid * 32 * 128;

    float acc[32];
#pragma unroll
    for (int i = 0; i < 32; ++i) acc[i] = 0.f;

    for (int kc = 0; kc < 4; ++kc) {          // K chunks of 32
        float xr[32];
        if (act) {
#pragma unroll
            for (int j = 0; j < 8; ++j) {
                const float4 v = xg[kc * 8 + j];
                xr[j * 4 + 0] = v.x; xr[j * 4 + 1] = v.y;
                xr[j * 4 + 2] = v.z; xr[j * 4 + 3] = v.w;
            }
        } else {
#pragma unroll
            for (int k = 0; k < 32; ++k) xr[k] = 0.f;
        }
#pragma unroll
        for (int o = 0; o < 32; ++o) {
            const float* __restrict__ wr = Wb + o * 128 + kc * 32;  // wave-uniform
            float a = acc[o];
#pragma unroll
            for (int k = 0; k < 32; ++k) a = fmaf(xr[k], wr[k], a);
            acc[o] = a;
        }
    }

    if (act) {
        uint4* __restrict__ xto = (uint4*)xt16 + (long)n * 16 + wid * 4;
#pragma unroll
        for (int j = 0; j < 4; ++j) {
            uint4 v;
            v.x = (unsigned)f2bf(acc[j * 8 + 0]) | ((unsigned)f2bf(acc[j * 8 + 1]) << 16);
            v.y = (unsigned)f2bf(acc[j * 8 + 2]) | ((unsigned)f2bf(acc[j * 8 + 3]) << 16);
            v.z = (unsigned)f2bf(acc[j * 8 + 4]) | ((unsigned)f2bf(acc[j * 8 + 5]) << 16);
            v.w = (unsigned)f2bf(acc[j * 8 + 6]) | ((unsigned)f2bf(acc[j * 8 + 7]) << 16);
            xto[j] = v;
        }
        float vs = 0.f, vd = 0.f;
#pragma unroll
        for (int i = 0; i < 32; ++i) {
            vs = fmaf(acc[i], avs[wid * 32 + i], vs);  // uniform -> s_load
            vd = fmaf(acc[i], avd[wid * 32 + i], vd);
        }
        ss[n * 4 + wid] = vs;
        sd[n * 4 + wid] = vd;
    }
}

// ---------- exclusive scan over deg (3 passes) ----------
__device__ __forceinline__ int block_excl_scan(int v, int tid, int* total) {
    const int lane = tid & 63, wv = tid >> 6;
    int incl = v;
#pragma unroll
    for (int m = 1; m < 64; m <<= 1) {
        int t = __shfl_up(incl, m);
        if (lane >= m) incl += t;
    }
    __shared__ int wt[4];
    if (lane == 63) wt[wv] = incl;
    __syncthreads();
    int wofs = 0;
#pragma unroll
    for (int i = 0; i < 4; ++i) if (i < wv) wofs += wt[i];
    if (total) *total = wt[0] + wt[1] + wt[2] + wt[3];
    return incl - v + wofs;
}

__launch_bounds__(256)
__global__ void k_scan1(const int* __restrict__ deg, int* __restrict__ psum, int N) {
    const int i = blockIdx.x * 256 + threadIdx.x;
    int v = (i < N) ? deg[i] : 0;
    int total;
    block_excl_scan(v, threadIdx.x, &total);
    if (threadIdx.x == 0) psum[blockIdx.x] = total;
}

__launch_bounds__(256)
__global__ void k_scan2(int* __restrict__ psum, int* __restrict__ bofs, int NB) {
    const int t = threadIdx.x;
    int v = (t < NB) ? psum[t] : 0;
    int excl = block_excl_scan(v, t, nullptr);
    if (t < NB) bofs[t] = excl;
}

__launch_bounds__(256)
__global__ void k_scan3(const int* __restrict__ bofs, int* __restrict__ degcur,
                        int* __restrict__ row, int N, int E) {
    const int i = blockIdx.x * 256 + threadIdx.x;
    int v = (i < N) ? degcur[i] : 0;
    int excl = block_excl_scan(v, threadIdx.x, nullptr);
    const int r = bofs[blockIdx.x] + excl;
    if (i < N) {
        row[i] = r;
        degcur[i] = r;   // cursor init (aliases deg; safe: value consumed above)
    }
    if (i == 0) row[N] = E;
}

// ---------- placement: bucket src ids by dst (4B/edge scatter only) ----------
__launch_bounds__(256)
__global__ void k_place(const void* __restrict__ ei, int* __restrict__ cursor,
                        int* __restrict__ srcs, long E) {
    const int is64 = detect64((const int*)ei);
    const long e = (long)blockIdx.x * 256 + threadIdx.x;
    if (e >= E) return;
    long s, d;
    load_edge(ei, is64, E, e, &s, &d);
    const int pos = atomicAdd(&cursor[(int)d], 1);
    srcs[pos] = (int)s;
}

// ---------- per-dst gather: recompute weights in-register, unnormalized out,
//            per-block per-head weight partials (deterministic final sum) ----------
// (no max shift: scores O(+-12), exp fp32-safe; validated R4/R5)
__launch_bounds__(256)
__global__ void k_gather(const int* __restrict__ srcs, const float* __restrict__ ss,
                         const float* __restrict__ sd, const int* __restrict__ row,
                         const unsigned* __restrict__ xt16, float* __restrict__ out,
                         float* __restrict__ psums, int N) {
    const int nb = blockIdx.x;
    const int wv = threadIdx.x >> 6;
    const int l = threadIdx.x & 63;
    const int h = l >> 4;                   // features 2l,2l+1 -> head (2l)>>5
    const int n = nb * 4 + wv;
    float wsum = 0.f;
    if (n < N) {
        const int beg = __builtin_amdgcn_readfirstlane(row[n]);
        const int end = __builtin_amdgcn_readfirstlane(row[n + 1]);
        const float sdh = sd[n * 4 + h];
        float accx = 0.f, accy = 0.f;
        for (int i = beg; i < end; ++i) {
            const int s = srcs[i];                      // uniform -> s_load
            float sc = ss[s * 4 + h] + sdh;             // 16-lane broadcast load
            sc = sc > 0.f ? sc : 0.2f * sc;
            const float wt = __expf(sc);
            const unsigned u = xt16[(long)s * 64 + l];  // coalesced bf16x2 row
            accx = fmaf(wt, __uint_as_float(u << 16), accx);          // feat 2l
            accy = fmaf(wt, __uint_as_float(u & 0xFFFF0000u), accy);  // feat 2l+1
            wsum += wt;
        }
        ((float2*)out)[(long)n * 64 + l] = make_float2(accx, accy);
    }
    // per-block partial: wsum identical across the 16 lanes of a head group
    __shared__ float sm[4][4];
    if ((l & 15) == 0) sm[wv][h] = wsum;
    __syncthreads();
    if (threadIdx.x < 4) {
        const int hh = threadIdx.x;
        psums[(long)nb * 4 + hh] = (sm[0][hh] + sm[1][hh]) + (sm[2][hh] + sm[3][hh]);
    }
}

// ---------- final reduce of partials -> inv[h] (deterministic) ----------
__launch_bounds__(256)
__global__ void k_finsum(const float4* __restrict__ psums, float* __restrict__ inv,
                         int NP) {
    float4 a = make_float4(0.f, 0.f, 0.f, 0.f);
    for (int i = threadIdx.x; i < NP; i += 256) {
        const float4 v = psums[i];
        a.x += v.x; a.y += v.y; a.z += v.z; a.w += v.w;
    }
#pragma unroll
    for (int m = 32; m; m >>= 1) {
        a.x += __shfl_xor(a.x, m);
        a.y += __shfl_xor(a.y, m);
        a.z += __shfl_xor(a.z, m);
        a.w += __shfl_xor(a.w, m);
    }
    __shared__ float sm[4][4];
    const int wv = threadIdx.x >> 6;
    if ((threadIdx.x & 63) == 0) {
        sm[wv][0] = a.x; sm[wv][1] = a.y; sm[wv][2] = a.z; sm[wv][3] = a.w;
    }
    __syncthreads();
    if (threadIdx.x < 4) {
        const int hh = threadIdx.x;
        inv[hh] = 1.0f / ((sm[0][hh] + sm[1][hh]) + (sm[2][hh] + sm[3][hh]));
    }
}

// ---------- normalize out by 1/sum[h] ----------
__launch_bounds__(256)
__global__ void k_norm(float* __restrict__ out, const float* __restrict__ inv,
                       long NP2) {                      // NP2 = N*64 float2 elems
    const long i = (long)blockIdx.x * 256 + threadIdx.x;
    if (i >= NP2) return;
    const int h = ((int)i & 63) >> 4;
    const float s = inv[h];
    float2 v = ((const float2*)out)[i];
    ((float2*)out)[i] = make_float2(v.x * s, v.y * s);
}

extern "C" void kernel_launch(void* const* d_in, const int* in_sizes, int n_in,
                              void* d_out, int out_size, void* d_ws, size_t ws_size,
                              hipStream_t stream) {
    const float* x     = (const float*)d_in[0];
    const void*  ei    = d_in[1];
    const float* W     = (const float*)d_in[2];
    const float* a_src = (const float*)d_in[3];
    const float* a_dst = (const float*)d_in[4];
    const long N = in_sizes[0] / 128;
    const long E = in_sizes[1] / 2;
    const int NB = (int)((N + 255) / 256);
    const int NG = (int)((N + 63) / 64);          // gemm blocks
    const int NH = (int)((E + 255) / 256);        // histogram / edge blocks
    const int NGB = (int)((N + 3) / 4);           // gather blocks

    char* p = (char*)d_ws;
    auto alloc = [&](size_t bytes) { char* r = p; p += (bytes + 15) & ~(size_t)15; return r; };
    unsigned* xt16   = (unsigned*)alloc(N * 64 * 4);   // bf16x2 packed, [N][64] uints
    float*    ss     = (float*)alloc(N * 4 * 4);
    float*    sd     = (float*)alloc(N * 4 * 4);
    int*      deg    = (int*)alloc(N * 4);             // reused as cursor after scan
    int*      row    = (int*)alloc((N + 1) * 4);
    int*      psum   = (int*)alloc(NB * 4);
    int*      bofs   = (int*)alloc(NB * 4);
    int*      srcs   = (int*)alloc(E * 4);
    float*    psums  = (float*)alloc((size_t)NGB * 4 * 4);
    float*    inv    = (float*)alloc(4 * 4);

    float* out = (float*)d_out;

    hipMemsetAsync(deg, 0, N * 4, stream);

    k_gemm_hist<<<(unsigned)(NG + NH), 256, 0, stream>>>(x, W, a_src, a_dst, ei, xt16,
                                                         ss, sd, deg, (int)N, NG, E);
    k_scan1<<<(unsigned)NB, 256, 0, stream>>>(deg, psum, (int)N);
    k_scan2<<<1, 256, 0, stream>>>(psum, bofs, NB);
    k_scan3<<<(unsigned)NB, 256, 0, stream>>>(bofs, deg, row, (int)N, (int)E);
    k_place<<<(unsigned)NH, 256, 0, stream>>>(ei, deg, srcs, E);
    k_gather<<<(unsigned)NGB, 256, 0, stream>>>(srcs, ss, sd, row, xt16, out,
                                                psums, (int)N);
    k_finsum<<<1, 256, 0, stream>>>((const float4*)psums, inv, NGB);
    k_norm<<<(unsigned)((N * 64 + 255) / 256), 256, 0, stream>>>(out, inv, N * 64);
}